// Round 3
// baseline (1675.757 us; speedup 1.0000x reference)
//
#include <hip/hip_runtime.h>
#include <math.h>

#define CC 32

static inline int cdiv(long long a, int b) { return (int)((a + b - 1) / b); }

// ---------- degree histogram: deg[src]+=1 (norm), cnt[dst]+=1 (CSR) ----------
__global__ void k_degcnt(const int* __restrict__ src, const int* __restrict__ dst,
                         float* __restrict__ deg, int* __restrict__ cnt, int E) {
  int i = blockIdx.x * blockDim.x + threadIdx.x;
  if (i < E) {
    atomicAdd(&deg[src[i]], 1.0f);
    atomicAdd(&cnt[dst[i]], 1);
  }
}

__global__ void k_dis(float* __restrict__ dis, int N) {
  int i = blockIdx.x * blockDim.x + threadIdx.x;
  if (i < N) {
    float d = dis[i];
    dis[i] = (d > 0.f) ? rsqrtf(fmaxf(d, 1.f)) : 0.f;
  }
}

// ---------- single-block exclusive scan of cnt -> rowptr, cur ----------
__global__ void k_scan(const int* __restrict__ cnt, int* __restrict__ rowptr,
                       int* __restrict__ cur, int N) {
  const int T = 1024;
  __shared__ int ps[T];
  int t = threadIdx.x;
  int chunk = (N + T - 1) / T;
  int lo = t * chunk, hi = min(lo + chunk, N);
  int s = 0;
  for (int i = lo; i < hi; ++i) s += cnt[i];
  ps[t] = s;
  __syncthreads();
  for (int off = 1; off < T; off <<= 1) {
    int v = (t >= off) ? ps[t - off] : 0;
    __syncthreads();
    ps[t] += v;
    __syncthreads();
  }
  int run = (t == 0) ? 0 : ps[t - 1];
  for (int i = lo; i < hi; ++i) {
    rowptr[i] = run;
    cur[i] = run;
    run += cnt[i];
  }
  if (t == T - 1) rowptr[N] = run;
}

// ---------- CSR fill: col[pos]=src, wcsr[pos]=-dis[s]*dis[d] ----------
__global__ void k_fill(const int* __restrict__ src, const int* __restrict__ dst,
                       const float* __restrict__ dis, int* __restrict__ cur,
                       int* __restrict__ col, float* __restrict__ wcsr, int E) {
  int i = blockIdx.x * blockDim.x + threadIdx.x;
  if (i < E) {
    int s = src[i], d = dst[i];
    int p = atomicAdd(&cur[d], 1);
    col[p] = s;
    wcsr[p] = -dis[s] * dis[d];
  }
}

// ---------- fused Cheb propagation + GEMM accumulate ----------
// Txk[g] = scale * sum_in w*x[s]  (+ prevscale*prev[g]); chebacc[g] += Txk[g]@W
// FIRST: chebacc[g] = bias + patch[g]@W0 + Tx1[g]@W1 (x==patch)
template <int FIRST>
__global__ void k_prop(const float* __restrict__ x, const float* __restrict__ prev,
                       const int* __restrict__ rowptr, const int* __restrict__ col,
                       const float* __restrict__ wcsr, const float* __restrict__ W,
                       const float* __restrict__ bias, float* __restrict__ out,
                       float* __restrict__ chebacc, float scale, float prevscale, int N) {
  __shared__ float w0[1024];
  __shared__ float w1[FIRST ? 1024 : 1];
  for (int i = threadIdx.x; i < 1024; i += blockDim.x) {
    w0[i] = W[i];
    if (FIRST) w1[i] = W[1024 + i];
  }
  __syncthreads();
  int g = (blockIdx.x * blockDim.x + threadIdx.x) >> 5;
  int c = threadIdx.x & 31;
  if (g >= N) return;
  int lo = rowptr[g], hi = rowptr[g + 1];
  float acc = 0.f;
  for (int j = lo; j < hi; ++j) {
    int s = col[j];
    float w = wcsr[j];
    acc = fmaf(w, x[(long long)s * 32 + c], acc);
  }
  acc *= scale;
  if (!FIRST) acc = fmaf(prevscale, prev[(long long)g * 32 + c], acc);
  out[(long long)g * 32 + c] = acc;

  float o;
  if (FIRST) {
    o = bias[c];
    float p = x[(long long)g * 32 + c];
#pragma unroll
    for (int cc = 0; cc < 32; ++cc) {
      float a = __shfl(p, cc, 32);
      o = fmaf(a, w0[cc * 32 + c], o);
    }
#pragma unroll
    for (int cc = 0; cc < 32; ++cc) {
      float a = __shfl(acc, cc, 32);
      o = fmaf(a, w1[cc * 32 + c], o);
    }
  } else {
    o = chebacc[(long long)g * 32 + c];
#pragma unroll
    for (int cc = 0; cc < 32; ++cc) {
      float a = __shfl(acc, cc, 32);
      o = fmaf(a, w0[cc * 32 + c], o);
    }
  }
  chebacc[(long long)g * 32 + c] = o;
}

// ---------- dense h = x @ lin_w (OUTC=64) ----------
template <int OUTC>
__global__ void k_gemm(const float* __restrict__ T, const float* __restrict__ W,
                       float* __restrict__ out, int N) {
  __shared__ float w[32 * OUTC];
  for (int i = threadIdx.x; i < 32 * OUTC; i += blockDim.x) w[i] = W[i];
  __syncthreads();
  const int ROWS = 256 / OUTC;
  int row = blockIdx.x * ROWS + threadIdx.x / OUTC;
  int col = threadIdx.x % OUTC;
  if (row >= N) return;
  const float* tr = T + (long long)row * 32;
  float acc = 0.f;
#pragma unroll
  for (int c = 0; c < 32; ++c) acc += tr[c] * w[c * OUTC + col];
  out[(long long)row * OUTC + col] = acc;
}

// ---------- proj vectors: pl_hd = lin_w[:,hd]@att_l[hd], pr_hd similarly ----------
__global__ void k_proj(const float* __restrict__ lin_w, const float* __restrict__ attl,
                       const float* __restrict__ attr, float* __restrict__ proj) {
  int t = threadIdx.x;
  if (t < 128) {
    int v = t >> 5, c = t & 31;  // v: 0=al h0, 1=al h1, 2=ar h0, 3=ar h1
    int hd = v & 1;
    const float* att = (v < 2) ? attl : attr;
    float s = 0.f;
    for (int j = 0; j < 32; ++j) s += lin_w[c * 64 + hd * 32 + j] * att[hd * 32 + j];
    proj[v * 32 + c] = s;
  }
}

// ---------- per-node attention terms: natt[g] = {al0, al1, ar0, ar1} ----------
__global__ void k_nodeatt(const float* __restrict__ x, const float* __restrict__ proj,
                          float* __restrict__ natt, int N) {
  __shared__ float pj[128];
  if (threadIdx.x < 128) pj[threadIdx.x] = proj[threadIdx.x];
  __syncthreads();
  int g = (blockIdx.x * blockDim.x + threadIdx.x) >> 5;
  int c = threadIdx.x & 31;
  if (g >= N) return;
  float xv = x[(long long)g * 32 + c];
  float d0 = xv * pj[c], d1 = xv * pj[32 + c], d2 = xv * pj[64 + c], d3 = xv * pj[96 + c];
#pragma unroll
  for (int m = 16; m; m >>= 1) {
    d0 += __shfl_xor(d0, m, 32);
    d1 += __shfl_xor(d1, m, 32);
    d2 += __shfl_xor(d2, m, 32);
    d3 += __shfl_xor(d3, m, 32);
  }
  if (c == 0) {
    float4* o = (float4*)(natt + (long long)g * 4);
    *o = make_float4(d0, d1, d2, d3);
  }
}

// ---------- SuperGAT gather: one wave per dst node, online softmax, fused epilogue ----------
__global__ void k_gat(const float* __restrict__ h, const int* __restrict__ rowptr,
                      const int* __restrict__ col, const float* __restrict__ natt,
                      const float* __restrict__ gb, float* __restrict__ y,
                      float* __restrict__ bns, int N) {
  __shared__ float ls[64];
  if (threadIdx.x < 64) ls[threadIdx.x] = 0.f;
  __syncthreads();
  int wv = (blockIdx.x * blockDim.x + threadIdx.x) >> 6;  // node
  int lane = threadIdx.x & 63;
  int c = lane & 31, hd = lane >> 5;
  bool active = wv < N;
  float yv = 0.f;
  if (active) {
    float hown = h[(long long)wv * 64 + lane];
    float arown = natt[wv * 4 + 2 + hd];
    // self-loop
    float dt = hown * hown;
#pragma unroll
    for (int m = 16; m; m >>= 1) dt += __shfl_xor(dt, m, 32);
    float a = (natt[wv * 4 + hd] + arown) / (1.f + __expf(-dt));
    a = (a > 0.f) ? a : 0.2f * a;
    float m_run = a, l_run = 1.f, acc = hown;
    int lo = rowptr[wv], hi = rowptr[wv + 1];
    for (int j = lo; j < hi; ++j) {
      int s = col[j];
      float hs = h[(long long)s * 64 + lane];
      float d2 = hown * hs;
#pragma unroll
      for (int m = 16; m; m >>= 1) d2 += __shfl_xor(d2, m, 32);
      float ae = (natt[s * 4 + hd] + arown) / (1.f + __expf(-d2));
      ae = (ae > 0.f) ? ae : 0.2f * ae;
      float mnew = fmaxf(m_run, ae);
      float sc = __expf(m_run - mnew);
      float f = __expf(ae - mnew);
      l_run = l_run * sc + f;
      acc = acc * sc + f * hs;
      m_run = mnew;
    }
    float o = acc / l_run;
    float o2 = __shfl_xor(o, 32, 64);  // partner head
    if (hd == 0) {
      float v = 0.5f * (o + o2) + gb[c];
      yv = ((v > 0.f) ? v : 0.01f * v) + v;
      y[(long long)wv * 32 + c] = yv;
    }
  }
  if (hd == 0) {
    atomicAdd(&ls[c], yv);
    atomicAdd(&ls[32 + c], yv * yv);
  }
  __syncthreads();
  if (threadIdx.x < 64) atomicAdd(&bns[threadIdx.x], ls[threadIdx.x]);
}

// in-place safe (y may alias out)
__global__ void k_bnfinal(const float* __restrict__ y, const float* __restrict__ bns,
                          const float* __restrict__ g, const float* __restrict__ b,
                          float* __restrict__ out, int N) {
  int i = blockIdx.x * blockDim.x + threadIdx.x;
  if (i >= N * CC) return;
  int c = i & 31;
  float inv_n = 1.f / (float)N;
  float mu = bns[c] * inv_n;
  float var = bns[32 + c] * inv_n - mu * mu;
  out[i] = (y[i] - mu) * rsqrtf(var + 1e-5f) * g[c] + b[c];
}

extern "C" void kernel_launch(void* const* d_in, const int* in_sizes, int n_in,
                              void* d_out, int out_size, void* d_ws, size_t ws_size,
                              hipStream_t stream) {
  const float* patch = (const float*)d_in[0];
  const int* eidx = (const int*)d_in[1];
  // d_in[2] = edge_attr (unused)
  const float* cheb_w = (const float*)d_in[3];
  const float* cheb_b = (const float*)d_in[4];
  const float* lin_w = (const float*)d_in[5];
  const float* att_l = (const float*)d_in[6];
  const float* att_r = (const float*)d_in[7];
  const float* gat_b = (const float*)d_in[8];
  const float* bn_g = (const float*)d_in[9];
  const float* bn_b = (const float*)d_in[10];
  float* out = (float*)d_out;

  const int N = in_sizes[0] / CC;  // 100000
  const int E = in_sizes[1] / 2;   // 1600000
  const int* src = eidx;
  const int* dst = eidx + E;

  // workspace: ~10.4M words = 42 MB
  float* h = (float*)d_ws;                    // N*64 (TxA=h, TxB=h+N*32 during cheb)
  float* TxA = h;
  float* TxB = h + (size_t)N * 32;
  int* col = (int*)(h + (size_t)N * 64);      // E
  float* wcsr = (float*)(col + E);            // E
  int* rowptr = (int*)(wcsr + E);             // N+1
  int* cur = rowptr + N + 1;                  // N
  int* cnt = cur + N;                         // N
  float* deg = (float*)(cnt + N);             // N (dis in place)
  float* natt = deg + N;                      // N*4
  float* proj = natt + (size_t)N * 4;         // 128
  float* bns = proj + 128;                    // 64

  const int B = 256;
  const long long NC = (long long)N * 32;

  hipMemsetAsync(cnt, 0, sizeof(int) * (size_t)N * 2, stream);  // cnt + deg
  hipMemsetAsync(bns, 0, sizeof(float) * 64, stream);

  // CSR build + normalization
  k_degcnt<<<cdiv(E, B), B, 0, stream>>>(src, dst, deg, cnt, E);
  k_dis<<<cdiv(N, B), B, 0, stream>>>(deg, N);
  k_scan<<<1, 1024, 0, stream>>>(cnt, rowptr, cur, N);
  k_fill<<<cdiv(E, B), B, 0, stream>>>(src, dst, deg, cur, col, wcsr, E);

  // ChebConv (fused prop + gemm accumulate into d_out)
  k_prop<1><<<cdiv(NC, B), B, 0, stream>>>(patch, nullptr, rowptr, col, wcsr,
                                           cheb_w, cheb_b, TxA, out, 1.f, 0.f, N);
  k_prop<0><<<cdiv(NC, B), B, 0, stream>>>(TxA, patch, rowptr, col, wcsr,
                                           cheb_w + 2 * 1024, nullptr, TxB, out, 2.f, -1.f, N);
  k_prop<0><<<cdiv(NC, B), B, 0, stream>>>(TxB, TxA, rowptr, col, wcsr,
                                           cheb_w + 3 * 1024, nullptr, TxA, out, 2.f, -1.f, N);
  k_prop<0><<<cdiv(NC, B), B, 0, stream>>>(TxA, TxB, rowptr, col, wcsr,
                                           cheb_w + 4 * 1024, nullptr, TxB, out, 2.f, -1.f, N);

  // SuperGAT
  k_gemm<64><<<cdiv(N, 4), B, 0, stream>>>(out, lin_w, h, N);  // h overlays TxA/TxB (dead)
  k_proj<<<1, 128, 0, stream>>>(lin_w, att_l, att_r, proj);
  k_nodeatt<<<cdiv(NC, B), B, 0, stream>>>(out, proj, natt, N);
  k_gat<<<cdiv(N, 4), B, 0, stream>>>(h, rowptr, col, natt, gat_b, out, bns, N);

  // BatchNorm finalize (in place on d_out)
  k_bnfinal<<<cdiv(NC, B), B, 0, stream>>>(out, bns, bn_g, bn_b, out, N);
}

// Round 4
// 1582.537 us; speedup vs baseline: 1.0589x; 1.0589x over previous
//
#include <hip/hip_runtime.h>
#include <math.h>

#define CC 32

static inline int cdiv(long long a, int b) { return (int)((a + b - 1) / b); }

// ---------- degree histogram: deg[src]+=1 (norm), cnt[dst]+=1 (CSR) ----------
__global__ void k_degcnt(const int* __restrict__ src, const int* __restrict__ dst,
                         float* __restrict__ deg, int* __restrict__ cnt, int E) {
  int i = blockIdx.x * blockDim.x + threadIdx.x;
  if (i < E) {
    atomicAdd(&deg[src[i]], 1.0f);
    atomicAdd(&cnt[dst[i]], 1);
  }
}

__global__ void k_dis(float* __restrict__ dis, int N) {
  int i = blockIdx.x * blockDim.x + threadIdx.x;
  if (i < N) {
    float d = dis[i];
    dis[i] = (d > 0.f) ? rsqrtf(fmaxf(d, 1.f)) : 0.f;
  }
}

// ---------- single-block exclusive scan of cnt -> rowptr, cur ----------
__global__ void k_scan(const int* __restrict__ cnt, int* __restrict__ rowptr,
                       int* __restrict__ cur, int N) {
  const int T = 1024;
  __shared__ int ps[T];
  int t = threadIdx.x;
  int chunk = (N + T - 1) / T;
  int lo = t * chunk, hi = min(lo + chunk, N);
  int s = 0;
  for (int i = lo; i < hi; ++i) s += cnt[i];
  ps[t] = s;
  __syncthreads();
  for (int off = 1; off < T; off <<= 1) {
    int v = (t >= off) ? ps[t - off] : 0;
    __syncthreads();
    ps[t] += v;
    __syncthreads();
  }
  int run = (t == 0) ? 0 : ps[t - 1];
  for (int i = lo; i < hi; ++i) {
    rowptr[i] = run;
    cur[i] = run;
    run += cnt[i];
  }
  if (t == T - 1) rowptr[N] = run;
}

// ---------- CSR fill: col[pos]=src, wcsr[pos]=-dis[s]*dis[d] ----------
__global__ void k_fill(const int* __restrict__ src, const int* __restrict__ dst,
                       const float* __restrict__ dis, int* __restrict__ cur,
                       int* __restrict__ col, float* __restrict__ wcsr, int E) {
  int i = blockIdx.x * blockDim.x + threadIdx.x;
  if (i < E) {
    int s = src[i], d = dst[i];
    int p = atomicAdd(&cur[d], 1);
    col[p] = s;
    wcsr[p] = -dis[s] * dis[d];
  }
}

// ---------- fused Cheb propagation + GEMM accumulate (8-way unrolled gather) ----------
template <int FIRST>
__global__ void k_prop(const float* __restrict__ x, const float* __restrict__ prev,
                       const int* __restrict__ rowptr, const int* __restrict__ col,
                       const float* __restrict__ wcsr, const float* __restrict__ W,
                       const float* __restrict__ bias, float* __restrict__ out,
                       float* __restrict__ chebacc, float scale, float prevscale, int N) {
  __shared__ float w0[1024];
  __shared__ float w1[FIRST ? 1024 : 1];
  for (int i = threadIdx.x; i < 1024; i += blockDim.x) {
    w0[i] = W[i];
    if (FIRST) w1[i] = W[1024 + i];
  }
  __syncthreads();
  int g = (blockIdx.x * blockDim.x + threadIdx.x) >> 5;
  int c = threadIdx.x & 31;
  if (g >= N) return;
  int lo = rowptr[g], hi = rowptr[g + 1];
  float acc = 0.f;
  for (int j = lo; j < hi; j += 8) {
    int rem = hi - j;
    float xv[8], ww[8];
#pragma unroll
    for (int e = 0; e < 8; ++e) {
      int jj = (e < rem) ? (j + e) : j;
      int s = col[jj];
      ww[e] = (e < rem) ? wcsr[jj] : 0.f;
      xv[e] = x[(long long)s * 32 + c];
    }
#pragma unroll
    for (int e = 0; e < 8; ++e) acc = fmaf(ww[e], xv[e], acc);
  }
  acc *= scale;
  if (!FIRST) acc = fmaf(prevscale, prev[(long long)g * 32 + c], acc);
  out[(long long)g * 32 + c] = acc;

  float o;
  if (FIRST) {
    o = bias[c];
    float p = x[(long long)g * 32 + c];
#pragma unroll
    for (int cc = 0; cc < 32; ++cc) {
      float a = __shfl(p, cc, 32);
      o = fmaf(a, w0[cc * 32 + c], o);
    }
#pragma unroll
    for (int cc = 0; cc < 32; ++cc) {
      float a = __shfl(acc, cc, 32);
      o = fmaf(a, w1[cc * 32 + c], o);
    }
  } else {
    o = chebacc[(long long)g * 32 + c];
#pragma unroll
    for (int cc = 0; cc < 32; ++cc) {
      float a = __shfl(acc, cc, 32);
      o = fmaf(a, w0[cc * 32 + c], o);
    }
  }
  chebacc[(long long)g * 32 + c] = o;
}

// ---------- dense h = x @ lin_w (OUTC=64) ----------
template <int OUTC>
__global__ void k_gemm(const float* __restrict__ T, const float* __restrict__ W,
                       float* __restrict__ out, int N) {
  __shared__ float w[32 * OUTC];
  for (int i = threadIdx.x; i < 32 * OUTC; i += blockDim.x) w[i] = W[i];
  __syncthreads();
  const int ROWS = 256 / OUTC;
  int row = blockIdx.x * ROWS + threadIdx.x / OUTC;
  int col = threadIdx.x % OUTC;
  if (row >= N) return;
  const float* tr = T + (long long)row * 32;
  float acc = 0.f;
#pragma unroll
  for (int c = 0; c < 32; ++c) acc += tr[c] * w[c * OUTC + col];
  out[(long long)row * OUTC + col] = acc;
}

// ---------- proj vectors: pl_hd = lin_w[:,hd]@att_l[hd], pr_hd similarly ----------
__global__ void k_proj(const float* __restrict__ lin_w, const float* __restrict__ attl,
                       const float* __restrict__ attr, float* __restrict__ proj) {
  int t = threadIdx.x;
  if (t < 128) {
    int v = t >> 5, c = t & 31;  // v: 0=al h0, 1=al h1, 2=ar h0, 3=ar h1
    int hd = v & 1;
    const float* att = (v < 2) ? attl : attr;
    float s = 0.f;
    for (int j = 0; j < 32; ++j) s += lin_w[c * 64 + hd * 32 + j] * att[hd * 32 + j];
    proj[v * 32 + c] = s;
  }
}

// ---------- per-node attention terms: natt[g] = {al0, al1, ar0, ar1} ----------
__global__ void k_nodeatt(const float* __restrict__ x, const float* __restrict__ proj,
                          float* __restrict__ natt, int N) {
  __shared__ float pj[128];
  if (threadIdx.x < 128) pj[threadIdx.x] = proj[threadIdx.x];
  __syncthreads();
  int g = (blockIdx.x * blockDim.x + threadIdx.x) >> 5;
  int c = threadIdx.x & 31;
  if (g >= N) return;
  float xv = x[(long long)g * 32 + c];
  float d0 = xv * pj[c], d1 = xv * pj[32 + c], d2 = xv * pj[64 + c], d3 = xv * pj[96 + c];
#pragma unroll
  for (int m = 16; m; m >>= 1) {
    d0 += __shfl_xor(d0, m, 32);
    d1 += __shfl_xor(d1, m, 32);
    d2 += __shfl_xor(d2, m, 32);
    d3 += __shfl_xor(d3, m, 32);
  }
  if (c == 0) {
    float4* o = (float4*)(natt + (long long)g * 4);
    *o = make_float4(d0, d1, d2, d3);
  }
}

// ---------- SuperGAT gather: one wave per node, 8 edges/iter (8 lanes each) ----------
// lane = e*8+q : slot e in [0,8), q indexes 4-channel chunks. Online softmax batched.
__global__ void k_gat(const float* __restrict__ h, const int* __restrict__ rowptr,
                      const int* __restrict__ col, const float* __restrict__ natt,
                      const float* __restrict__ gb, float* __restrict__ y,
                      float* __restrict__ bns, int N) {
  __shared__ float ls[64];
  if (threadIdx.x < 64) ls[threadIdx.x] = 0.f;
  __syncthreads();
  int wv = (blockIdx.x * blockDim.x + threadIdx.x) >> 6;
  int lane = threadIdx.x & 63;
  int e = lane >> 3, q = lane & 7;
  if (wv < N) {
    const float4* hrow = (const float4*)(h + (long long)wv * 64);
    float4 own0 = hrow[q], own1 = hrow[8 + q];
    const float4 na = *(const float4*)(natt + (long long)wv * 4);  // {al0,al1,ar0,ar1}
    // self-loop attention
    float d0 = own0.x * own0.x + own0.y * own0.y + own0.z * own0.z + own0.w * own0.w;
    float d1 = own1.x * own1.x + own1.y * own1.y + own1.z * own1.z + own1.w * own1.w;
#pragma unroll
    for (int m = 1; m <= 4; m <<= 1) { d0 += __shfl_xor(d0, m); d1 += __shfl_xor(d1, m); }
    float a0 = (na.x + na.z) / (1.f + __expf(-d0));
    float a1 = (na.y + na.w) / (1.f + __expf(-d1));
    a0 = (a0 > 0.f) ? a0 : 0.2f * a0;
    a1 = (a1 > 0.f) ? a1 : 0.2f * a1;
    float m0 = a0, m1 = a1;
    float sel = (e == 0) ? 1.f : 0.f;
    float l0 = sel, l1 = sel;
    float4 acc0 = make_float4(own0.x * sel, own0.y * sel, own0.z * sel, own0.w * sel);
    float4 acc1 = make_float4(own1.x * sel, own1.y * sel, own1.z * sel, own1.w * sel);
    int lo = rowptr[wv], hi = rowptr[wv + 1];
    for (int j = lo; j < hi; j += 8) {
      int jj = j + e;
      bool valid = jj < hi;
      int s = col[valid ? jj : (hi - 1)];
      const float4* hs = (const float4*)(h + (long long)s * 64);
      float4 h0 = hs[q], h1 = hs[8 + q];
      float2 al = *(const float2*)(natt + (long long)s * 4);
      float t0 = h0.x * own0.x + h0.y * own0.y + h0.z * own0.z + h0.w * own0.w;
      float t1 = h1.x * own1.x + h1.y * own1.y + h1.z * own1.z + h1.w * own1.w;
#pragma unroll
      for (int m = 1; m <= 4; m <<= 1) { t0 += __shfl_xor(t0, m); t1 += __shfl_xor(t1, m); }
      float ae0 = (al.x + na.z) / (1.f + __expf(-t0));
      float ae1 = (al.y + na.w) / (1.f + __expf(-t1));
      ae0 = (ae0 > 0.f) ? ae0 : 0.2f * ae0;
      ae1 = (ae1 > 0.f) ? ae1 : 0.2f * ae1;
      if (!valid) { ae0 = -1e30f; ae1 = -1e30f; }
      float b0 = ae0, b1 = ae1;
#pragma unroll
      for (int m = 8; m <= 32; m <<= 1) {
        b0 = fmaxf(b0, __shfl_xor(b0, m));
        b1 = fmaxf(b1, __shfl_xor(b1, m));
      }
      float mn0 = fmaxf(m0, b0), mn1 = fmaxf(m1, b1);
      float sc0 = __expf(m0 - mn0), sc1 = __expf(m1 - mn1);
      float f0 = __expf(ae0 - mn0), f1 = __expf(ae1 - mn1);
      l0 = l0 * sc0 + f0;
      l1 = l1 * sc1 + f1;
      acc0.x = acc0.x * sc0 + f0 * h0.x; acc0.y = acc0.y * sc0 + f0 * h0.y;
      acc0.z = acc0.z * sc0 + f0 * h0.z; acc0.w = acc0.w * sc0 + f0 * h0.w;
      acc1.x = acc1.x * sc1 + f1 * h1.x; acc1.y = acc1.y * sc1 + f1 * h1.y;
      acc1.z = acc1.z * sc1 + f1 * h1.z; acc1.w = acc1.w * sc1 + f1 * h1.w;
      m0 = mn0; m1 = mn1;
    }
    // reduce across the 8 edge slots
#pragma unroll
    for (int m = 8; m <= 32; m <<= 1) {
      l0 += __shfl_xor(l0, m); l1 += __shfl_xor(l1, m);
      acc0.x += __shfl_xor(acc0.x, m); acc0.y += __shfl_xor(acc0.y, m);
      acc0.z += __shfl_xor(acc0.z, m); acc0.w += __shfl_xor(acc0.w, m);
      acc1.x += __shfl_xor(acc1.x, m); acc1.y += __shfl_xor(acc1.y, m);
      acc1.z += __shfl_xor(acc1.z, m); acc1.w += __shfl_xor(acc1.w, m);
    }
    if (e == 0) {
      float r0 = 1.f / l0, r1 = 1.f / l1;
      const float4 gb4 = *(const float4*)(gb + q * 4);
      float4 yv;
      float v;
      v = 0.5f * (acc0.x * r0 + acc1.x * r1) + gb4.x; yv.x = ((v > 0.f) ? v : 0.01f * v) + v;
      v = 0.5f * (acc0.y * r0 + acc1.y * r1) + gb4.y; yv.y = ((v > 0.f) ? v : 0.01f * v) + v;
      v = 0.5f * (acc0.z * r0 + acc1.z * r1) + gb4.z; yv.z = ((v > 0.f) ? v : 0.01f * v) + v;
      v = 0.5f * (acc0.w * r0 + acc1.w * r1) + gb4.w; yv.w = ((v > 0.f) ? v : 0.01f * v) + v;
      *(float4*)(y + (long long)wv * 32 + q * 4) = yv;
      atomicAdd(&ls[q * 4 + 0], yv.x); atomicAdd(&ls[32 + q * 4 + 0], yv.x * yv.x);
      atomicAdd(&ls[q * 4 + 1], yv.y); atomicAdd(&ls[32 + q * 4 + 1], yv.y * yv.y);
      atomicAdd(&ls[q * 4 + 2], yv.z); atomicAdd(&ls[32 + q * 4 + 2], yv.z * yv.z);
      atomicAdd(&ls[q * 4 + 3], yv.w); atomicAdd(&ls[32 + q * 4 + 3], yv.w * yv.w);
    }
  }
  __syncthreads();
  if (threadIdx.x < 64) atomicAdd(&bns[threadIdx.x], ls[threadIdx.x]);
}

// in-place safe (y may alias out)
__global__ void k_bnfinal(const float* __restrict__ y, const float* __restrict__ bns,
                          const float* __restrict__ g, const float* __restrict__ b,
                          float* __restrict__ out, int N) {
  int i = blockIdx.x * blockDim.x + threadIdx.x;
  if (i >= N * CC) return;
  int c = i & 31;
  float inv_n = 1.f / (float)N;
  float mu = bns[c] * inv_n;
  float var = bns[32 + c] * inv_n - mu * mu;
  out[i] = (y[i] - mu) * rsqrtf(var + 1e-5f) * g[c] + b[c];
}

extern "C" void kernel_launch(void* const* d_in, const int* in_sizes, int n_in,
                              void* d_out, int out_size, void* d_ws, size_t ws_size,
                              hipStream_t stream) {
  const float* patch = (const float*)d_in[0];
  const int* eidx = (const int*)d_in[1];
  // d_in[2] = edge_attr (unused)
  const float* cheb_w = (const float*)d_in[3];
  const float* cheb_b = (const float*)d_in[4];
  const float* lin_w = (const float*)d_in[5];
  const float* att_l = (const float*)d_in[6];
  const float* att_r = (const float*)d_in[7];
  const float* gat_b = (const float*)d_in[8];
  const float* bn_g = (const float*)d_in[9];
  const float* bn_b = (const float*)d_in[10];
  float* out = (float*)d_out;

  const int N = in_sizes[0] / CC;  // 100000
  const int E = in_sizes[1] / 2;   // 1600000
  const int* src = eidx;
  const int* dst = eidx + E;

  // workspace: ~10.4M words = 42 MB (natt kept 16B-aligned via rowptr pad to N+4)
  float* h = (float*)d_ws;                    // N*64 (TxA=h, TxB=h+N*32 during cheb)
  float* TxA = h;
  float* TxB = h + (size_t)N * 32;
  int* col = (int*)(h + (size_t)N * 64);      // E
  float* wcsr = (float*)(col + E);            // E
  int* rowptr = (int*)(wcsr + E);             // N+4 (padded for alignment)
  int* cur = rowptr + N + 4;                  // N
  int* cnt = cur + N;                         // N
  float* deg = (float*)(cnt + N);             // N (dis in place)
  float* natt = deg + N;                      // N*4 (16B aligned)
  float* proj = natt + (size_t)N * 4;         // 128
  float* bns = proj + 128;                    // 64

  const int B = 256;
  const long long NC = (long long)N * 32;

  hipMemsetAsync(cnt, 0, sizeof(int) * (size_t)N * 2, stream);  // cnt + deg
  hipMemsetAsync(bns, 0, sizeof(float) * 64, stream);

  // CSR build + normalization
  k_degcnt<<<cdiv(E, B), B, 0, stream>>>(src, dst, deg, cnt, E);
  k_dis<<<cdiv(N, B), B, 0, stream>>>(deg, N);
  k_scan<<<1, 1024, 0, stream>>>(cnt, rowptr, cur, N);
  k_fill<<<cdiv(E, B), B, 0, stream>>>(src, dst, deg, cur, col, wcsr, E);

  // ChebConv (fused prop + gemm accumulate into d_out)
  k_prop<1><<<cdiv(NC, B), B, 0, stream>>>(patch, nullptr, rowptr, col, wcsr,
                                           cheb_w, cheb_b, TxA, out, 1.f, 0.f, N);
  k_prop<0><<<cdiv(NC, B), B, 0, stream>>>(TxA, patch, rowptr, col, wcsr,
                                           cheb_w + 2 * 1024, nullptr, TxB, out, 2.f, -1.f, N);
  k_prop<0><<<cdiv(NC, B), B, 0, stream>>>(TxB, TxA, rowptr, col, wcsr,
                                           cheb_w + 3 * 1024, nullptr, TxA, out, 2.f, -1.f, N);
  k_prop<0><<<cdiv(NC, B), B, 0, stream>>>(TxA, TxB, rowptr, col, wcsr,
                                           cheb_w + 4 * 1024, nullptr, TxB, out, 2.f, -1.f, N);

  // SuperGAT
  k_gemm<64><<<cdiv(N, 4), B, 0, stream>>>(out, lin_w, h, N);  // h overlays TxA/TxB (dead)
  k_proj<<<1, 128, 0, stream>>>(lin_w, att_l, att_r, proj);
  k_nodeatt<<<cdiv(NC, B), B, 0, stream>>>(out, proj, natt, N);
  k_gat<<<cdiv(N, 4), B, 0, stream>>>(h, rowptr, col, natt, gat_b, out, bns, N);

  // BatchNorm finalize (in place on d_out)
  k_bnfinal<<<cdiv(NC, B), B, 0, stream>>>(out, bns, bn_g, bn_b, out, N);
}